// Round 5
// baseline (433.520 us; speedup 1.0000x reference)
//
#include <hip/hip_runtime.h>

// EquivariantProductBasisBlock (MACE symmetric contraction, corr=3) + o3.Linear
// N=10000 nodes, C=128 channels, L=9 (lmax=2), E=5 elements, fp32 throughout.
//
// R18 changes vs R17:
//  - R17 evidence: linear is LDS-PIPE-bound (per-CU single pipe: 8 waves x
//    ~70cy/cl demand vs 128cy VALU capacity -> ~4x over). Fix: no LDS in the
//    GEMM loop at all. W lives in VGPRs (thread = (c1,dd) owns its output
//    column, wt[128], loaded once via a small LDS transpose prologue). A is
//    read via wave-uniform s_load broadcast (contract's proven SMEM trick):
//    contract now writes tmpT[p][ci][dd] (contiguous 512-dword node records,
//    float4 per thread via a 4KB LDS shuffle). Inner loop = 128 FMA/node
//    with one SGPR operand; zero VMEM/LDS.
//  - Grid 256 blocks x 512 thr = 1 block/CU, 2 waves/SIMD, ~40 nodes/block.
//    Output rows staged in an 8-row LDS buffer, flushed float4 + sc.

#define CCH 128
#define LDIM 9
#define NE 5
#define BLK 256
#define TSTR 220             // coeffs per (e,c,dd): 219 + 1 pad (16B-aligned)
#define TGSTR 880            // per (e,c) = 4*TSTR
#define U3LDS 8748           // staged U3 slice (729*12 max)

// -------------------------------------------- sort: count + offs (fused)
__global__ __launch_bounds__(BLK) void count_offs_kernel(
    const float* __restrict__ attrs, int N,
    int* __restrict__ elem, int* __restrict__ gcnt,   // gcnt[5], gcnt[5]=done
    int* __restrict__ offs, int* __restrict__ cur) {
  int n = blockIdx.x * BLK + threadIdx.x;
  int e = 0;
  if (n < N) {
    const float* a = attrs + n * NE;
#pragma unroll
    for (int j = 1; j < NE; ++j)
      if (a[j] > 0.5f) e = j;
    elem[n] = e;
  }
  int lane = threadIdx.x & 63;
#pragma unroll
  for (int k = 0; k < NE; ++k) {
    unsigned long long m = __ballot(n < N && e == k);
    if (m) {
      int leader = __ffsll((long long)m) - 1;
      if (lane == leader) atomicAdd(&gcnt[k], __popcll(m));
    }
  }
  __threadfence();
  __syncthreads();
  if (threadIdx.x == 0) {
    int t = atomicAdd(&gcnt[NE], 1);
    if (t == (int)gridDim.x - 1) {            // last block: prefix sum
      int acc = 0;
      for (int k = 0; k < NE; ++k) {
        int ck = atomicAdd(&gcnt[k], 0);      // coherent read
        offs[k] = acc; cur[k] = acc; acc += ck;
      }
      offs[NE] = acc;
    }
  }
}

// ----------------------------------------------------------- sort: scatter
__global__ __launch_bounds__(BLK) void scatter_kernel(
    const int* __restrict__ elem, int N,
    int* __restrict__ cur, int* __restrict__ order) {
  int n = blockIdx.x * BLK + threadIdx.x;
  if (n >= N) return;
  int e = elem[n];
  int lane = threadIdx.x & 63;
#pragma unroll
  for (int k = 0; k < NE; ++k) {
    if (e == k) {
      unsigned long long m = __ballot(1);
      int cnt = __popcll(m);
      int leader = __ffsll((long long)m) - 1;
      int base = 0;
      if (lane == leader) base = atomicAdd(&cur[k], cnt);
      base = __shfl(base, leader);
      int rank = __popcll(m & ((1ull << lane) - 1ull));
      order[base + rank] = n;
    }
  }
}

// ---- build + FULLY (u,v,w)-symmetrize + pack U(x)w tables (one dd/block)
__global__ __launch_bounds__(BLK) void table_kernel(
    const float* __restrict__ U3_0, const float* __restrict__ U2_0,
    const float* __restrict__ U1_0, const float* __restrict__ U3_1,
    const float* __restrict__ U2_1, const float* __restrict__ U1_1,
    const float* __restrict__ w3_0, const float* __restrict__ w2_0,
    const float* __restrict__ w1_0, const float* __restrict__ w3_1,
    const float* __restrict__ w2_1, const float* __restrict__ w1_1,
    float* __restrict__ table) {
  const int b = blockIdx.x;        // e*CCH + c
  const int dd = blockIdx.y;       // 0..3
  const int e = b / CCH, c = b % CCH;
  float* Tg = table + (size_t)b * TGSTR + dd * TSTR;
  __shared__ float Us[U3LDS];      // raw U3 slice [729*K3]
  __shared__ float U2s[324];       // raw U2 slice [81*K2]
  __shared__ float R3[729];        // rect T3
  __shared__ float R2[81];
  __shared__ float R1l[9];
  __shared__ float w3l[12], w2l[4];
  const int tid = threadIdx.x;
  const int d = dd - 1;
  const int K3 = (dd == 0) ? 10 : 12;
  const int K2 = (dd == 0) ? 3 : 4;

  if (dd == 0) {
    for (int i = tid; i < 7290; i += BLK) Us[i] = U3_0[i];
    for (int i = tid; i < 243; i += BLK)  U2s[i] = U2_0[i];
    if (tid < 10) w3l[tid] = w3_0[(e * 10 + tid) * CCH + c];
    else if (tid < 13) w2l[tid - 10] = w2_0[(e * 3 + (tid - 10)) * CCH + c];
    if (tid < 9) R1l[tid] = U1_0[tid] * w1_0[e * CCH + c];
  } else {
    for (int i = tid; i < 8748; i += BLK) Us[i] = U3_1[d * 8748 + i];
    for (int i = tid; i < 324; i += BLK)  U2s[i] = U2_1[d * 324 + i];
    if (tid < 12) w3l[tid] = w3_1[(e * 12 + tid) * CCH + c];
    else if (tid < 16) w2l[tid - 12] = w2_1[(e * 4 + (tid - 12)) * CCH + c];
    if (tid < 9) R1l[tid] = U1_1[d * 9 + tid] * w1_1[e * CCH + c];
  }
  __syncthreads();
  for (int r = tid; r < 729; r += BLK) {
    float acc = 0.f;
    for (int k = 0; k < K3; ++k) acc += Us[r * K3 + k] * w3l[k];
    R3[r] = acc;
  }
  for (int q = tid; q < 81; q += BLK) {
    float acc = 0.f;
    for (int k = 0; k < K2; ++k) acc += U2s[q * K2 + k] * w2l[k];
    R2[q] = acc;
  }
  __syncthreads();
  // pack: Horner consumption order. Per u: [T1s[u], then per v=u..8:
  //   [T2s[u][v], S3s[u][v][w] for w=v..8]].  Per-u size = (10-u)(11-u)/2.
  for (int i = tid; i < TSTR; i += BLK) {
    float val = 0.f;
    if (i < 219) {
      int rem = i, u = 0;
      while (rem >= (10 - u) * (11 - u) / 2) {
        rem -= (10 - u) * (11 - u) / 2; ++u;
      }
      if (rem == 0) {
        val = R1l[u];
      } else {
        rem -= 1;
        int v = u;
        while (rem >= 10 - v) { rem -= 10 - v; ++v; }
        if (rem == 0) {
          val = (u == v) ? R2[u * 9 + v] : R2[u * 9 + v] + R2[v * 9 + u];
        } else {
          int w = v + (rem - 1);
          if (u == v && v == w)
            val = R3[(u * 9 + u) * 9 + u];
          else if (u == v)
            val = R3[(u * 9 + u) * 9 + w] + R3[(u * 9 + w) * 9 + u] +
                  R3[(w * 9 + u) * 9 + u];
          else if (v == w)
            val = R3[(u * 9 + v) * 9 + v] + R3[(v * 9 + u) * 9 + v] +
                  R3[(v * 9 + v) * 9 + u];
          else
            val = R3[(u * 9 + v) * 9 + w] + R3[(u * 9 + w) * 9 + v] +
                  R3[(v * 9 + u) * 9 + w] + R3[(v * 9 + w) * 9 + u] +
                  R3[(w * 9 + u) * 9 + v] + R3[(w * 9 + v) * 9 + u];
        }
      }
    }
    Tg[i] = val;
  }
}

// --- symmetric contraction: triangular Horner over fully-sym table.
//     thread = 1 node x 1 channel; cb via uniform s_load.
//     Epilogue: 4KB LDS shuffle -> float4 store to tmpT[p][ci][dd].
__global__ __launch_bounds__(BLK, 8) void contract_kernel(
    const float* __restrict__ feats, const float* __restrict__ table,
    const int* __restrict__ order, const int* __restrict__ offs,
    float* __restrict__ tmpT) {
  const int c = blockIdx.x;                   // 0..127
  // map global chunk -> (element e, node range) ; wave-uniform
  int rem = blockIdx.y;
  int e = -1, pbase = 0, segend = 0;
#pragma unroll
  for (int k = 0; k < NE; ++k) {
    int st = offs[k], en = offs[k + 1];
    int nc = (en - st + BLK - 1) >> 8;        // chunks in segment k (BLK=256)
    if (e < 0) {
      if (rem < nc) { e = k; pbase = st + rem * BLK; segend = en; }
      else rem -= nc;
    }
  }
  if (e < 0) return;                          // slack chunk

  const int p = pbase + threadIdx.x;
  const bool valid = (p < segend);
  const int n = order[valid ? p : (segend - 1)];  // clamp: stay in-bounds

  __shared__ float LT[4][BLK];                // dd-transpose staging

  float tf[LDIM];
  {
    const float* xp = feats + ((size_t)n * CCH + c) * LDIM;
#pragma unroll
    for (int q = 0; q < LDIM; ++q) tf[q] = xp[q];
  }

  const float* Tc = table + (size_t)(e * CCH + c) * TGSTR;

#pragma unroll 1
  for (int dd = 0; dd < 4; ++dd) {
    // wave-uniform address (blockIdx/dd only) -> s_load (SMEM path)
    const float* B = Tc + dd * TSTR;
    int idx = 0;                              // folds to constants on unroll
    float acc = 0.f;
#pragma unroll
    for (int u = 0; u < 9; ++u) {
      float inner = B[idx++];                 // T1s[u]
#pragma unroll
      for (int v = u; v < 9; ++v) {
        float Hv = B[idx++];                  // T2sym[u][v]
#pragma unroll
        for (int w = v; w < 9; ++w)
          Hv = fmaf(B[idx++], tf[w], Hv);
        inner = fmaf(Hv, tf[v], inner);
      }
      acc = fmaf(inner, tf[u], acc);
    }
    LT[dd][threadIdx.x] = acc;                // same-thread readback, no barrier
  }
  if (valid) {
    float4 v;
    v.x = LT[0][threadIdx.x];
    v.y = LT[1][threadIdx.x];
    v.z = LT[2][threadIdx.x];
    v.w = LT[3][threadIdx.x];
    *(float4*)(tmpT + (size_t)p * 512 + c * 4) = v;
  }
}

// ------------- o3.Linear + residual: W-in-VGPR, A via SMEM broadcast.
// thread = (c1 0..127, dd 0..3); 512 threads; grid = 256 (1 block/CU).
__global__ __launch_bounds__(512, 2) void linear_kernel(
    const float* __restrict__ tmpT, const float* __restrict__ W0,
    const float* __restrict__ W1, const float* __restrict__ sc,
    const int* __restrict__ order, float* __restrict__ out, int N) {
  const int t = threadIdx.x;
  const int pchunk = (N + 255) >> 8;          // nodes per block (grid=256)
  const int pbase = blockIdx.x * pchunk;
  const int pend  = min(pbase + pchunk, N);
  if (pbase >= pend) return;

  const int c1 = t & 127;
  const int dd = __builtin_amdgcn_readfirstlane(t >> 7);  // wave-uniform

  __shared__ __align__(16) float WS[4096];    // 16 KB W tile staging
  __shared__ __align__(16) float SROW[8 * 520]; // 8 output rows

  // ---- prologue: wt[ci] = (dd==0 ? W0 : W1)[ci][c1] via LDS transpose
  float wt[128];
#pragma unroll
  for (int tile = 0; tile < 8; ++tile) {
    ((float4*)WS)[t]       = ((const float4*)(W0 + tile * 2048))[t];
    ((float4*)WS)[512 + t] = ((const float4*)(W1 + tile * 2048))[t];
    __syncthreads();
    const float* base = WS + (dd ? 2048 : 0) + c1;
#pragma unroll
    for (int k = 0; k < 16; ++k)
      wt[tile * 16 + k] = base[k * 128];      // 2-way bank alias: free
    __syncthreads();
  }

  const int co_map = (dd == 0) ? c1 : (128 + c1 * 3 + (dd - 1));
  const float s = 0.08838834764831843f;       // 1/sqrt(128)

#pragma unroll 1
  for (int pb = pbase; pb < pend; pb += 8) {
#pragma unroll 1
    for (int i = 0; i < 8; ++i) {
      const int p = pb + i;                   // block-uniform
      if (p < pend) {
        const float* Ad = tmpT + (size_t)p * 512 + dd;  // uniform -> s_load
        float acc = 0.f;
#pragma unroll
        for (int cc = 0; cc < 32; ++cc) {
#pragma unroll
          for (int j = 0; j < 4; ++j)
            acc = fmaf(wt[cc * 4 + j], Ad[cc * 16 + j * 4], acc);
        }
        SROW[i * 520 + co_map] = acc * s;
      }
    }
    __syncthreads();
    // flush up to 8 rows, float4-coalesced, + sc residual
    const int r = t >> 6, f = t & 63;
    const int p2 = pb + r;
    if (p2 < pend) {
      const int n = order[p2];
      const float4* scp = (const float4*)(sc + (size_t)n * 512);
      float4* op = (float4*)(out + (size_t)n * 512);
#pragma unroll
      for (int q = 0; q < 2; ++q) {
        const int idx = f + q * 64;
        float4 v = *(const float4*)(SROW + r * 520 + idx * 4);
        float4 s4 = scp[idx];
        v.x += s4.x; v.y += s4.y; v.z += s4.z; v.w += s4.w;
        op[idx] = v;
      }
    }
    __syncthreads();
  }
}

// -------------------------------------------------------------------- launch
extern "C" void kernel_launch(void* const* d_in, const int* in_sizes, int n_in,
                              void* d_out, int out_size, void* d_ws, size_t ws_size,
                              hipStream_t stream) {
  const float* feats = (const float*)d_in[0];
  const float* attrs = (const float*)d_in[1];
  const float* sc    = (const float*)d_in[2];
  const float* U3_0  = (const float*)d_in[3];
  const float* U2_0  = (const float*)d_in[4];
  const float* U1_0  = (const float*)d_in[5];
  const float* w3_0  = (const float*)d_in[6];
  const float* w2_0  = (const float*)d_in[7];
  const float* w1_0  = (const float*)d_in[8];
  const float* U3_1  = (const float*)d_in[9];
  const float* U2_1  = (const float*)d_in[10];
  const float* U1_1  = (const float*)d_in[11];
  const float* w3_1  = (const float*)d_in[12];
  const float* w2_1  = (const float*)d_in[13];
  const float* w1_1  = (const float*)d_in[14];
  const float* W0    = (const float*)d_in[15];
  const float* W1    = (const float*)d_in[16];

  const int N = in_sizes[0] / (CCH * LDIM);     // 10000

  // ws (floats): table[5*128*TGSTR] | tmpT[N][512] | order elem offs(8) cur(8) gcnt(8)
  float* table = (float*)d_ws;
  float* tmpT  = table + (size_t)NE * CCH * TGSTR;
  int*   order = (int*)(tmpT + (size_t)N * 512);
  int*   elem  = order + N;
  int*   offs  = elem + N;
  int*   cur   = offs + 8;
  int*   gcnt  = cur + 8;                       // gcnt[0..4], gcnt[5]=done
  float* out   = (float*)d_out;

  hipMemsetAsync(gcnt, 0, 8 * sizeof(int), stream);

  const int nblk = (N + BLK - 1) / BLK;
  count_offs_kernel<<<dim3(nblk), dim3(BLK), 0, stream>>>(
      attrs, N, elem, gcnt, offs, cur);
  scatter_kernel<<<dim3(nblk), dim3(BLK), 0, stream>>>(elem, N, cur, order);

  table_kernel<<<dim3(NE * CCH, 4), dim3(BLK), 0, stream>>>(
      U3_0, U2_0, U1_0, U3_1, U2_1, U1_1,
      w3_0, w2_0, w1_0, w3_1, w2_1, w1_1, table);

  // compact chunk grid: sum over e of ceil(cnt_e/BLK) <= N/BLK + NE
  const int chunksMax = (N + BLK - 1) / BLK + NE;
  contract_kernel<<<dim3(CCH, chunksMax), dim3(BLK), 0, stream>>>(
      feats, table, order, offs, tmpT);

  linear_kernel<<<dim3(256), dim3(512), 0, stream>>>(
      tmpT, W0, W1, sc, order, out, N);
}

// Round 6
// 252.724 us; speedup vs baseline: 1.7154x; 1.7154x over previous
//
#include <hip/hip_runtime.h>

// EquivariantProductBasisBlock (MACE symmetric contraction, corr=3) + o3.Linear
// N=10000 nodes, C=128 channels, L=9 (lmax=2), E=5 elements, fp32 throughout.
//
// R19 changes vs R18:
//  - R18 post-mortem: wt[128]-in-VGPR spilled to scratch (VGPR=80 < 128
//    needed; liveness crossed 16 barriers) -> 236us. Reverted.
//  - linear rewrite on the R17 LDS+global_load_lds dbuf skeleton, but with
//    3x better FMA/LDS-read ratio: thread = 8 nodes x 8 co x 1 dd (dd =
//    wave index -> W-select wave-uniform). Per ci: 4x ds_read_b128 (48
//    wave-cyc) feeds 64 FMA. Block = 32 nodes x 512 outputs, grid 313.
//    A AND W both streamed per-16-ci chunks (A 8KB, W 16KB, dbuf = 48KB
//    -> 2 blocks/CU). LDS-pipe roofline ~12.5us, HBM ~10us.
//  - contract reverted verbatim to R16/R17 (tmp[dd][ci][NPAD] layout).

#define CCH 128
#define LDIM 9
#define NE 5
#define BLK 256
#define TSTR 220             // coeffs per (e,c,dd): 219 + 1 pad (16B-aligned)
#define TGSTR 880            // per (e,c) = 4*TSTR
#define U3LDS 8748           // staged U3 slice (729*12 max)

// -------------------------------------------- sort: count + offs (fused)
__global__ __launch_bounds__(BLK) void count_offs_kernel(
    const float* __restrict__ attrs, int N,
    int* __restrict__ elem, int* __restrict__ gcnt,   // gcnt[5], gcnt[5]=done
    int* __restrict__ offs, int* __restrict__ cur) {
  int n = blockIdx.x * BLK + threadIdx.x;
  int e = 0;
  if (n < N) {
    const float* a = attrs + n * NE;
#pragma unroll
    for (int j = 1; j < NE; ++j)
      if (a[j] > 0.5f) e = j;
    elem[n] = e;
  }
  int lane = threadIdx.x & 63;
#pragma unroll
  for (int k = 0; k < NE; ++k) {
    unsigned long long m = __ballot(n < N && e == k);
    if (m) {
      int leader = __ffsll((long long)m) - 1;
      if (lane == leader) atomicAdd(&gcnt[k], __popcll(m));
    }
  }
  __threadfence();
  __syncthreads();
  if (threadIdx.x == 0) {
    int t = atomicAdd(&gcnt[NE], 1);
    if (t == (int)gridDim.x - 1) {            // last block: prefix sum
      int acc = 0;
      for (int k = 0; k < NE; ++k) {
        int ck = atomicAdd(&gcnt[k], 0);      // coherent read
        offs[k] = acc; cur[k] = acc; acc += ck;
      }
      offs[NE] = acc;
    }
  }
}

// ----------------------------------------------------------- sort: scatter
__global__ __launch_bounds__(BLK) void scatter_kernel(
    const int* __restrict__ elem, int N,
    int* __restrict__ cur, int* __restrict__ order) {
  int n = blockIdx.x * BLK + threadIdx.x;
  if (n >= N) return;
  int e = elem[n];
  int lane = threadIdx.x & 63;
#pragma unroll
  for (int k = 0; k < NE; ++k) {
    if (e == k) {
      unsigned long long m = __ballot(1);
      int cnt = __popcll(m);
      int leader = __ffsll((long long)m) - 1;
      int base = 0;
      if (lane == leader) base = atomicAdd(&cur[k], cnt);
      base = __shfl(base, leader);
      int rank = __popcll(m & ((1ull << lane) - 1ull));
      order[base + rank] = n;
    }
  }
}

// ---- build + FULLY (u,v,w)-symmetrize + pack U(x)w tables (one dd/block)
__global__ __launch_bounds__(BLK) void table_kernel(
    const float* __restrict__ U3_0, const float* __restrict__ U2_0,
    const float* __restrict__ U1_0, const float* __restrict__ U3_1,
    const float* __restrict__ U2_1, const float* __restrict__ U1_1,
    const float* __restrict__ w3_0, const float* __restrict__ w2_0,
    const float* __restrict__ w1_0, const float* __restrict__ w3_1,
    const float* __restrict__ w2_1, const float* __restrict__ w1_1,
    float* __restrict__ table) {
  const int b = blockIdx.x;        // e*CCH + c
  const int dd = blockIdx.y;       // 0..3
  const int e = b / CCH, c = b % CCH;
  float* Tg = table + (size_t)b * TGSTR + dd * TSTR;
  __shared__ float Us[U3LDS];      // raw U3 slice [729*K3]
  __shared__ float U2s[324];       // raw U2 slice [81*K2]
  __shared__ float R3[729];        // rect T3
  __shared__ float R2[81];
  __shared__ float R1l[9];
  __shared__ float w3l[12], w2l[4];
  const int tid = threadIdx.x;
  const int d = dd - 1;
  const int K3 = (dd == 0) ? 10 : 12;
  const int K2 = (dd == 0) ? 3 : 4;

  if (dd == 0) {
    for (int i = tid; i < 7290; i += BLK) Us[i] = U3_0[i];
    for (int i = tid; i < 243; i += BLK)  U2s[i] = U2_0[i];
    if (tid < 10) w3l[tid] = w3_0[(e * 10 + tid) * CCH + c];
    else if (tid < 13) w2l[tid - 10] = w2_0[(e * 3 + (tid - 10)) * CCH + c];
    if (tid < 9) R1l[tid] = U1_0[tid] * w1_0[e * CCH + c];
  } else {
    for (int i = tid; i < 8748; i += BLK) Us[i] = U3_1[d * 8748 + i];
    for (int i = tid; i < 324; i += BLK)  U2s[i] = U2_1[d * 324 + i];
    if (tid < 12) w3l[tid] = w3_1[(e * 12 + tid) * CCH + c];
    else if (tid < 16) w2l[tid - 12] = w2_1[(e * 4 + (tid - 12)) * CCH + c];
    if (tid < 9) R1l[tid] = U1_1[d * 9 + tid] * w1_1[e * CCH + c];
  }
  __syncthreads();
  for (int r = tid; r < 729; r += BLK) {
    float acc = 0.f;
    for (int k = 0; k < K3; ++k) acc += Us[r * K3 + k] * w3l[k];
    R3[r] = acc;
  }
  for (int q = tid; q < 81; q += BLK) {
    float acc = 0.f;
    for (int k = 0; k < K2; ++k) acc += U2s[q * K2 + k] * w2l[k];
    R2[q] = acc;
  }
  __syncthreads();
  // pack: Horner consumption order. Per u: [T1s[u], then per v=u..8:
  //   [T2s[u][v], S3s[u][v][w] for w=v..8]].  Per-u size = (10-u)(11-u)/2.
  for (int i = tid; i < TSTR; i += BLK) {
    float val = 0.f;
    if (i < 219) {
      int rem = i, u = 0;
      while (rem >= (10 - u) * (11 - u) / 2) {
        rem -= (10 - u) * (11 - u) / 2; ++u;
      }
      if (rem == 0) {
        val = R1l[u];
      } else {
        rem -= 1;
        int v = u;
        while (rem >= 10 - v) { rem -= 10 - v; ++v; }
        if (rem == 0) {
          val = (u == v) ? R2[u * 9 + v] : R2[u * 9 + v] + R2[v * 9 + u];
        } else {
          int w = v + (rem - 1);
          if (u == v && v == w)
            val = R3[(u * 9 + u) * 9 + u];
          else if (u == v)
            val = R3[(u * 9 + u) * 9 + w] + R3[(u * 9 + w) * 9 + u] +
                  R3[(w * 9 + u) * 9 + u];
          else if (v == w)
            val = R3[(u * 9 + v) * 9 + v] + R3[(v * 9 + u) * 9 + v] +
                  R3[(v * 9 + v) * 9 + u];
          else
            val = R3[(u * 9 + v) * 9 + w] + R3[(u * 9 + w) * 9 + v] +
                  R3[(v * 9 + u) * 9 + w] + R3[(v * 9 + w) * 9 + u] +
                  R3[(w * 9 + u) * 9 + v] + R3[(w * 9 + v) * 9 + u];
        }
      }
    }
    Tg[i] = val;
  }
}

// --- symmetric contraction: triangular Horner over fully-sym table.
//     thread = 1 node x 1 channel; no LDS; cb via uniform s_load.
//     blockIdx.y = global chunk -> (e, segment) via offs (compact grid).
__global__ __launch_bounds__(BLK, 8) void contract_kernel(
    const float* __restrict__ feats, const float* __restrict__ table,
    const int* __restrict__ order, const int* __restrict__ offs,
    float* __restrict__ tmp, int NPAD) {
  const int c = blockIdx.x;                   // 0..127
  // map global chunk -> (element e, node range) ; wave-uniform
  int rem = blockIdx.y;
  int e = -1, pbase = 0, segend = 0;
#pragma unroll
  for (int k = 0; k < NE; ++k) {
    int st = offs[k], en = offs[k + 1];
    int nc = (en - st + BLK - 1) >> 8;        // chunks in segment k (BLK=256)
    if (e < 0) {
      if (rem < nc) { e = k; pbase = st + rem * BLK; segend = en; }
      else rem -= nc;
    }
  }
  if (e < 0) return;                          // slack chunk

  const int p = pbase + threadIdx.x;
  const bool valid = (p < segend);
  const int n = order[valid ? p : (segend - 1)];  // clamp: stay in-bounds

  float tf[LDIM];
  {
    const float* xp = feats + ((size_t)n * CCH + c) * LDIM;
#pragma unroll
    for (int q = 0; q < LDIM; ++q) tf[q] = xp[q];
  }

  const float* Tc = table + (size_t)(e * CCH + c) * TGSTR;

#pragma unroll 1
  for (int dd = 0; dd < 4; ++dd) {
    // wave-uniform address (blockIdx/dd only) -> s_load (SMEM path)
    const float* B = Tc + dd * TSTR;
    int idx = 0;                              // folds to constants on unroll
    float acc = 0.f;
#pragma unroll
    for (int u = 0; u < 9; ++u) {
      float inner = B[idx++];                 // T1s[u]
#pragma unroll
      for (int v = u; v < 9; ++v) {
        float Hv = B[idx++];                  // T2sym[u][v]
#pragma unroll
        for (int w = v; w < 9; ++w)
          Hv = fmaf(B[idx++], tf[w], Hv);
        inner = fmaf(Hv, tf[v], inner);
      }
      acc = fmaf(inner, tf[u], acc);
    }
    if (valid) tmp[((size_t)dd * CCH + c) * NPAD + p] = acc;
  }
}

// ------------- o3.Linear + residual: LDS-tiled GEMM, A and W streamed via
//               global_load_lds double-buffer; thread = 8n x 8co x 1dd.
#define LNB 32                // nodes per linear block
// LDS float map: Abuf[2] @ [0,2048)+(b*2048)?  -> A b: [b*2048, b*2048+2048)
//   A chunk layout: row = cl*4+ddr (64 rows x 32 floats)
// Wbuf[2] @ [4096 + b*4096): row = cl*2+mat (32 rows x 128 floats)
// epilogue overlay: SROW 16 rows x 520 floats @ [0, 8320)
__global__ __launch_bounds__(BLK, 2) void linear_kernel(
    const float* __restrict__ tmp, const float* __restrict__ W0,
    const float* __restrict__ W1, const float* __restrict__ sc,
    const int* __restrict__ order, float* __restrict__ out, int N, int NPAD) {
  const int p0 = blockIdx.x * LNB;
  const int t = threadIdx.x;
  const int wave = t >> 6, lane = t & 63;
  __shared__ __align__(16) float LB[12288];   // 48 KB

  const int nq = t & 3;          // node-octet 0..3 (8 nodes each)
  const int oq = (t >> 2) & 15;  // co-octet 0..15 (8 co each)
  const int dd = wave;           // 0..3; wave-uniform W0/W1 select

  // ---- DMA: A chunk kk into buf b (64 rows x 128B; 2 calls/wave)
#define ISSUE_A(KK, B)                                                       \
  {                                                                          \
    float* Ab = LB + (B) * 2048;                                             \
    _Pragma("unroll")                                                        \
    for (int qq = 0; qq < 2; ++qq) {                                         \
      const int q = wave * 2 + qq;                                           \
      const int row = q * 8 + (lane >> 3);                                   \
      const int ci = (KK) * 16 + (row >> 2);                                 \
      const float* src = tmp +                                               \
          ((size_t)((row & 3) * CCH + ci) * NPAD + p0) + (lane & 7) * 4;     \
      __builtin_amdgcn_global_load_lds(src, Ab + q * 256 + lane * 4, 16, 0, 0); \
    }                                                                        \
  }
  // ---- DMA: W chunk kk into buf b (32 rows x 512B; 4 calls/wave)
#define ISSUE_W(KK, B)                                                       \
  {                                                                          \
    float* Wb = LB + 4096 + (B) * 4096;                                      \
    _Pragma("unroll")                                                        \
    for (int qq = 0; qq < 4; ++qq) {                                         \
      const int q = wave * 4 + qq;                                           \
      const int row = q * 2 + (lane >> 5);                                   \
      const int ci = (KK) * 16 + (row >> 1);                                 \
      const float* src =                                                     \
          ((row & 1) ? W1 : W0) + (size_t)ci * CCH + (lane & 31) * 4;        \
      __builtin_amdgcn_global_load_lds(src, Wb + q * 256 + lane * 4, 16, 0, 0); \
    }                                                                        \
  }

  ISSUE_A(0, 0)
  ISSUE_W(0, 0)
  __syncthreads();                     // vmcnt(0) drained: chunk 0 ready

  float acc[8][8];
#pragma unroll
  for (int r = 0; r < 8; ++r)
#pragma unroll
    for (int k = 0; k < 8; ++k) acc[r][k] = 0.f;

#pragma unroll 1
  for (int kk = 0; kk < 8; ++kk) {
    if (kk < 7) {                      // issue chunk kk+1 into other buf
      ISSUE_A(kk + 1, (kk + 1) & 1)
      ISSUE_W(kk + 1, (kk + 1) & 1)
    }
    const float* Ab = LB + (kk & 1) * 2048;
    const float* Wb = LB + 4096 + (kk & 1) * 4096;
#pragma unroll 2
    for (int cl = 0; cl < 16; ++cl) {
      const float* ap = Ab + (cl * 4 + dd) * 32 + nq * 8;
      const float* wp = Wb + (cl * 2 + (dd ? 1 : 0)) * 128 + oq * 8;
      const float4 a0 = *(const float4*)(ap);
      const float4 a1 = *(const float4*)(ap + 4);
      const float4 w0 = *(const float4*)(wp);
      const float4 w1 = *(const float4*)(wp + 4);
      const float a[8] = {a0.x, a0.y, a0.z, a0.w, a1.x, a1.y, a1.z, a1.w};
      const float w[8] = {w0.x, w0.y, w0.z, w0.w, w1.x, w1.y, w1.z, w1.w};
#pragma unroll
      for (int r = 0; r < 8; ++r)
#pragma unroll
        for (int k = 0; k < 8; ++k)
          acc[r][k] = fmaf(a[r], w[k], acc[r][k]);
    }
    __syncthreads();   // chunk kk+1 drained (vmcnt(0)); buf kk free
  }

  // ---- epilogue: two half-batches of 16 rows via SROW overlay
  const float s = 0.08838834764831843f;        // 1/sqrt(128)
#pragma unroll 1
  for (int hb = 0; hb < 2; ++hb) {
    if ((nq >> 1) == hb) {             // threads holding local nodes hb*16..
      const int rbase = (nq & 1) * 8;
#pragma unroll
      for (int r = 0; r < 8; ++r) {
        float* Sj = LB + (rbase + r) * 520;
#pragma unroll
        for (int k = 0; k < 8; ++k) {
          const int co = oq * 8 + k;
          if (dd == 0) Sj[co] = acc[r][k] * s;
          else         Sj[CCH + co * 3 + (dd - 1)] = acc[r][k] * s;
        }
      }
    }
    __syncthreads();
    // flush 16 rows x 512 floats, float4-coalesced, + sc residual
    const int f = t & 127, rr = t >> 7;
#pragma unroll 1
    for (int jr = rr; jr < 16; jr += 2) {
      const int p = p0 + hb * 16 + jr;
      if (p < N) {
        const int n = order[p];
        float4 sv = ((const float4*)(sc + (size_t)n * 512))[f];
        float4 ov = *(const float4*)(LB + jr * 520 + f * 4);
        ov.x += sv.x; ov.y += sv.y; ov.z += sv.z; ov.w += sv.w;
        ((float4*)(out + (size_t)n * 512))[f] = ov;
      }
    }
    __syncthreads();
  }
#undef ISSUE_A
#undef ISSUE_W
}

// -------------------------------------------------------------------- launch
extern "C" void kernel_launch(void* const* d_in, const int* in_sizes, int n_in,
                              void* d_out, int out_size, void* d_ws, size_t ws_size,
                              hipStream_t stream) {
  const float* feats = (const float*)d_in[0];
  const float* attrs = (const float*)d_in[1];
  const float* sc    = (const float*)d_in[2];
  const float* U3_0  = (const float*)d_in[3];
  const float* U2_0  = (const float*)d_in[4];
  const float* U1_0  = (const float*)d_in[5];
  const float* w3_0  = (const float*)d_in[6];
  const float* w2_0  = (const float*)d_in[7];
  const float* w1_0  = (const float*)d_in[8];
  const float* U3_1  = (const float*)d_in[9];
  const float* U2_1  = (const float*)d_in[10];
  const float* U1_1  = (const float*)d_in[11];
  const float* w3_1  = (const float*)d_in[12];
  const float* w2_1  = (const float*)d_in[13];
  const float* w1_1  = (const float*)d_in[14];
  const float* W0    = (const float*)d_in[15];
  const float* W1    = (const float*)d_in[16];

  const int N = in_sizes[0] / (CCH * LDIM);     // 10000
  const int NPAD = ((N + 15) & ~15) + 16;       // 10016 = 313*32

  // ws (floats): table[5*128*TGSTR] | tmp[4*C][NPAD] | order elem offs(8) cur(8) gcnt(8)
  float* table = (float*)d_ws;
  float* tmp   = table + (size_t)NE * CCH * TGSTR;
  int*   order = (int*)(tmp + (size_t)4 * CCH * NPAD);
  int*   elem  = order + N;
  int*   offs  = elem + N;
  int*   cur   = offs + 8;
  int*   gcnt  = cur + 8;                       // gcnt[0..4], gcnt[5]=done
  float* out   = (float*)d_out;

  hipMemsetAsync(gcnt, 0, 8 * sizeof(int), stream);

  const int nblk = (N + BLK - 1) / BLK;
  count_offs_kernel<<<dim3(nblk), dim3(BLK), 0, stream>>>(
      attrs, N, elem, gcnt, offs, cur);
  scatter_kernel<<<dim3(nblk), dim3(BLK), 0, stream>>>(elem, N, cur, order);

  table_kernel<<<dim3(NE * CCH, 4), dim3(BLK), 0, stream>>>(
      U3_0, U2_0, U1_0, U3_1, U2_1, U1_1,
      w3_0, w2_0, w1_0, w3_1, w2_1, w1_1, table);

  // compact chunk grid: sum over e of ceil(cnt_e/BLK) <= N/BLK + NE
  const int chunksMax = (N + BLK - 1) / BLK + NE;
  contract_kernel<<<dim3(CCH, chunksMax), dim3(BLK), 0, stream>>>(
      feats, table, order, offs, tmp, NPAD);

  linear_kernel<<<dim3((N + LNB - 1) / LNB), dim3(BLK), 0, stream>>>(
      tmp, W0, W1, sc, order, out, N, NPAD);
}